// Round 13
// baseline (162.372 us; speedup 1.0000x reference)
//
#include <hip/hip_runtime.h>
#include <stdint.h>
#include <stddef.h>

typedef __bf16 bf16;
typedef __bf16 bf16x4 __attribute__((ext_vector_type(4)));
typedef __bf16 bf16x8 __attribute__((ext_vector_type(8)));
typedef float  f32x4  __attribute__((ext_vector_type(4)));
typedef float  f32x16 __attribute__((ext_vector_type(16)));
typedef float  f32x4v __attribute__((ext_vector_type(4)));

// async global->LDS, 16B per lane, wave-uniform LDS base + lane*16
__device__ __forceinline__ void gload_lds16(const void* g, void* lds) {
  __builtin_amdgcn_global_load_lds(
      (__attribute__((address_space(1))) void*)(uintptr_t)g,
      (__attribute__((address_space(3))) void*)lds,
      16, 0, 0);
}

// ---------------- conversion kernels ----------------

__global__ void cvt_f32_to_bf16(const float* __restrict__ in, bf16* __restrict__ out, int n) {
  int i = (blockIdx.x * blockDim.x + threadIdx.x) * 4;
  if (i >= n) return;
  f32x4v v = *reinterpret_cast<const f32x4v*>(in + i);
  bf16x4 o;
  o[0] = (bf16)v[0]; o[1] = (bf16)v[1]; o[2] = (bf16)v[2]; o[3] = (bf16)v[3];
  *reinterpret_cast<bf16x4*>(out + i) = o;
}

// in [R][C] f32  ->  out [C][R] bf16   (R,C multiples of 32)
__global__ void transpose_cvt(const float* __restrict__ in, bf16* __restrict__ out, int R, int C) {
  __shared__ bf16 tile[32][33];
  int c0 = blockIdx.x * 32, r0 = blockIdx.y * 32;
  int tx = threadIdx.x, ty = threadIdx.y;
  #pragma unroll
  for (int i = ty; i < 32; i += 8)
    tile[i][tx] = (bf16)in[(size_t)(r0 + i) * C + (c0 + tx)];
  __syncthreads();
  #pragma unroll
  for (int i = ty; i < 32; i += 8)
    out[(size_t)(c0 + i) * R + (r0 + tx)] = tile[tx][i];
}

// ---------------- GEMM 128^2 (2-barrier, proven) -- used for GEMM2 ---------

template <typename OT, bool BIAS>
__global__ __launch_bounds__(256) void gemm_abt(
    const bf16* __restrict__ A,   // [M][K]
    const bf16* __restrict__ Bt,  // [N][K]
    const float* __restrict__ bias,
    OT* __restrict__ C, int M, int N, int K)
{
  __shared__ bf16 As[128 * 64];
  __shared__ bf16 Bs[128 * 64];

  const int tid = threadIdx.x;
  const int w = tid >> 6, l = tid & 63;
  const int l15 = l & 15, l4 = l >> 4, l7 = l & 7;
  const int wr = w >> 1, wc = w & 1;

  const int nwgx = N >> 7;
  const int nwg  = (M >> 7) * nwgx;
  const int cpx  = nwg >> 3;
  const int bid  = blockIdx.x;
  const int swz  = (bid & 7) * cpx + (bid >> 3);
  const int m0 = (swz / nwgx) * 128, n0 = (swz % nwgx) * 128;

  f32x4 acc[4][4];
  #pragma unroll
  for (int i = 0; i < 4; i++)
    #pragma unroll
    for (int j = 0; j < 4; j++) acc[i][j] = (f32x4){0.f, 0.f, 0.f, 0.f};

  const int srow  = w * 8 + (l >> 3);
  const int sslot = (l & 7) ^ ((l >> 3) & 7);
  const int KT = K >> 6;

  for (int kt = 0; kt < KT; ++kt) {
    __syncthreads();
    const int kcol = kt * 64 + sslot * 8;
    #pragma unroll
    for (int p = 0; p < 4; ++p) {
      gload_lds16(A  + (size_t)(m0 + p * 32 + srow) * K + kcol,
                  (char*)As + p * 4096 + w * 1024);
      gload_lds16(Bt + (size_t)(n0 + p * 32 + srow) * K + kcol,
                  (char*)Bs + p * 4096 + w * 1024);
    }
    __syncthreads();

    #pragma unroll
    for (int kk = 0; kk < 2; ++kk) {
      const int coff = (kk * 32 + l4 * 8) ^ (l7 << 3);
      bf16x8 af[4], bq[4];
      #pragma unroll
      for (int m = 0; m < 4; ++m) {
        int r = wr * 64 + m * 16 + l15;
        af[m] = *reinterpret_cast<const bf16x8*>(&As[r * 64 + coff]);
      }
      #pragma unroll
      for (int n = 0; n < 4; ++n) {
        int r = wc * 64 + n * 16 + l15;
        bq[n] = *reinterpret_cast<const bf16x8*>(&Bs[r * 64 + coff]);
      }
      #pragma unroll
      for (int m = 0; m < 4; ++m)
        #pragma unroll
        for (int n = 0; n < 4; ++n)
          acc[m][n] = __builtin_amdgcn_mfma_f32_16x16x32_bf16(af[m], bq[n], acc[m][n], 0, 0, 0);
    }
  }

  #pragma unroll
  for (int m = 0; m < 4; ++m) {
    #pragma unroll
    for (int n = 0; n < 4; ++n) {
      int col = n0 + wc * 64 + n * 16 + l15;
      float bv = BIAS ? bias[col] : 0.f;
      #pragma unroll
      for (int j = 0; j < 4; ++j) {
        int row = m0 + wr * 64 + m * 16 + l4 * 4 + j;
        float v = acc[m][n][j] + bv;
        C[(size_t)row * N + col] = (OT)v;
      }
    }
  }
}

// ---------------- GEMM 256^2 counted-vmcnt 4-phase (T2+T3+T4+T5) -----------
// 512 threads = 8 waves (2M x 4N). Phase p=(mh,nh) computes C quadrant
// rows mh*128+wm*64..+63, cols nh*128+wn*32..+31 (16 MFMA) and consumes
// EXACTLY half-tiles A[mh], B[nh]. Staging: one half-tile per phase, one
// K-step ahead, issue order A-lo,B-lo,B-hi,A-hi. Per-wave issue arithmetic
// gives a uniform s_waitcnt vmcnt(6) at phases 0,1,2 (none at 3): each
// phase's needed half-tile is exactly "all but the 6 youngest loads", with
// >=3 phases of landing slack. Never drains to 0 in the main loop (the
// R9 drain-0 mistake = m218's "8-phase-with-drain0 ~ 1-phase").
// Single s_barrier per phase: every LDS region has >=2 barrier crossings
// between last read (drained by that wave's pre-MFMA lgkmcnt) and re-stage.
// asm volatile barriers with "memory" clobber pin the LDS reads after the
// barrier (raw s_barrier builtin carries no fence - rule #18 class).

template <typename OT, bool BIAS>
__global__ __launch_bounds__(512, 1) void gemm256(
    const bf16* __restrict__ A,   // [M][K]
    const bf16* __restrict__ Bt,  // [N][K]
    const float* __restrict__ bias,
    OT* __restrict__ C, int M, int N, int K)
{
  __shared__ bf16 As[2][256 * 64];
  __shared__ bf16 Bs[2][256 * 64];

  const int tid = threadIdx.x;
  const int w = tid >> 6, l = tid & 63;
  const int l15 = l & 15, l4 = l >> 4, l7 = l & 7;
  const int wm = w >> 2, wn = w & 3;

  const int nwgx = N >> 8;
  const int nwg  = (M >> 8) * nwgx;
  const int cpx  = nwg >> 3;
  const int bid  = blockIdx.x;
  const int swz  = (bid & 7) * cpx + (bid >> 3);
  const int m0 = (swz / nwgx) * 256, n0 = (swz % nwgx) * 256;

  f32x4 acc[8][4];   // [mh*4+i][nh*2+n2]
  #pragma unroll
  for (int i = 0; i < 8; i++)
    #pragma unroll
    for (int j = 0; j < 4; j++) acc[i][j] = (f32x4){0.f, 0.f, 0.f, 0.f};

  const int w8l   = w * 8 + (l >> 3);            // row 0..63 within a 64-row block
  const int sslot = (l & 7) ^ ((l >> 3) & 7);
  const int KT = K >> 6;

  // stage half-tile (2 gloads/thread). hoff: 0 = lo(rows/cols 0-127), 128 = hi
  #define STA(t, hoff)                                                          \
    _Pragma("unroll")                                                           \
    for (int q = 0; q < 2; ++q)                                                 \
      gload_lds16(A + (size_t)(m0 + (hoff) + q * 64 + w8l) * K + (t) * 64 + sslot * 8, \
                  (char*)As[(t) & 1] + (hoff) * 128 + q * 8192 + w * 1024);
  #define STB(t, hoff)                                                          \
    _Pragma("unroll")                                                           \
    for (int q = 0; q < 2; ++q)                                                 \
      gload_lds16(Bt + (size_t)(n0 + (hoff) + q * 64 + w8l) * K + (t) * 64 + sslot * 8, \
                  (char*)Bs[(t) & 1] + (hoff) * 128 + q * 8192 + w * 1024);

  // prologue: K-step 0, issue order A-lo, B-lo, B-hi, A-hi
  STA(0, 0); STB(0, 0); STB(0, 128); STA(0, 128);

  bf16x8 afr[4][2], bfr[2][2];

  #define PHASE(buf, mh, nh)                                                     \
    {                                                                            \
      __builtin_amdgcn_s_setprio(1);                                             \
      if ((nh) == 0) {                                                           \
        _Pragma("unroll")                                                        \
        for (int i = 0; i < 4; ++i)                                              \
          _Pragma("unroll")                                                      \
          for (int kk = 0; kk < 2; ++kk) {                                       \
            int r = (mh) * 128 + wm * 64 + i * 16 + l15;                         \
            afr[i][kk] = *reinterpret_cast<const bf16x8*>(                       \
                &As[buf][r * 64 + (((kk * 4 + l4) ^ l7) * 8)]);                  \
          }                                                                      \
      }                                                                          \
      _Pragma("unroll")                                                          \
      for (int n2 = 0; n2 < 2; ++n2)                                             \
        _Pragma("unroll")                                                        \
        for (int kk = 0; kk < 2; ++kk) {                                         \
          int r = (nh) * 128 + wn * 32 + n2 * 16 + l15;                          \
          bfr[n2][kk] = *reinterpret_cast<const bf16x8*>(                        \
              &Bs[buf][r * 64 + (((kk * 4 + l4) ^ l7) * 8)]);                    \
        }                                                                        \
      _Pragma("unroll")                                                          \
      for (int i = 0; i < 4; ++i)                                                \
        _Pragma("unroll")                                                        \
        for (int n2 = 0; n2 < 2; ++n2)                                           \
          _Pragma("unroll")                                                      \
          for (int kk = 0; kk < 2; ++kk)                                         \
            acc[(mh) * 4 + i][(nh) * 2 + n2] =                                   \
                __builtin_amdgcn_mfma_f32_16x16x32_bf16(                         \
                    afr[i][kk], bfr[n2][kk], acc[(mh) * 4 + i][(nh) * 2 + n2],   \
                    0, 0, 0);                                                    \
      __builtin_amdgcn_s_setprio(0);                                             \
    }

  for (int t = 0; t < KT - 1; ++t) {
    const int buf = t & 1;
    // ph0 (0,0): stage A-lo(t+1)
    STA(t + 1, 0);
    asm volatile("s_waitcnt vmcnt(6)" ::: "memory");
    asm volatile("s_barrier" ::: "memory");
    PHASE(buf, 0, 0)
    // ph1 (0,1): stage B-lo(t+1)
    STB(t + 1, 0);
    asm volatile("s_waitcnt vmcnt(6)" ::: "memory");
    asm volatile("s_barrier" ::: "memory");
    PHASE(buf, 0, 1)
    // ph2 (1,0): stage B-hi(t+1)
    STB(t + 1, 128);
    asm volatile("s_waitcnt vmcnt(6)" ::: "memory");
    asm volatile("s_barrier" ::: "memory");
    PHASE(buf, 1, 0)
    // ph3 (1,1): stage A-hi(t+1); no wait needed (A-hi/B-hi already ensured)
    STA(t + 1, 128);
    asm volatile("s_barrier" ::: "memory");
    PHASE(buf, 1, 1)
  }

  // final K-step: everything staged; one drain, then pure compute
  asm volatile("s_waitcnt vmcnt(0)" ::: "memory");
  asm volatile("s_barrier" ::: "memory");
  {
    const int buf = (KT - 1) & 1;
    PHASE(buf, 0, 0)
    PHASE(buf, 0, 1)
    PHASE(buf, 1, 0)
    PHASE(buf, 1, 1)
  }
  #undef PHASE
  #undef STA
  #undef STB

  // epilogue
  #pragma unroll
  for (int mh = 0; mh < 2; ++mh)
    #pragma unroll
    for (int i = 0; i < 4; ++i)
      #pragma unroll
      for (int nh = 0; nh < 2; ++nh)
        #pragma unroll
        for (int n2 = 0; n2 < 2; ++n2) {
          int col = n0 + nh * 128 + wn * 32 + n2 * 16 + l15;
          float bv = BIAS ? bias[col] : 0.f;
          #pragma unroll
          for (int j = 0; j < 4; ++j) {
            int row = m0 + mh * 128 + wm * 64 + i * 16 + l4 * 4 + j;
            C[(size_t)row * N + col] = (OT)(acc[mh * 4 + i][nh * 2 + n2][j] + bv);
          }
        }
}

// ---------------- fused flash attention (32x32x16, 8-wave shared K/V) ------
// unchanged from R12 (best measured)

__global__ __launch_bounds__(512) void attn_fused(
    const bf16* __restrict__ qkv,
    bf16* __restrict__ aout)      // [8192][1024], col = h*64+d
{
  __shared__ bf16 Ks[64 * 64];
  __shared__ bf16 Vt[64 * 64];
  __shared__ bf16 Pl[8][32 * 64];

  const int tid = threadIdx.x;
  const int w = tid >> 6, l = tid & 63;
  const int l31 = l & 31, hi = l >> 5;

  const int bid = blockIdx.x;            // 512 blocks
  const int c  = bid & 7, rr = bid >> 3;
  const int g  = c * 16 + (rr & 15);
  const int qt = rr >> 4;
  const int h  = g & 15;
  const int b  = g >> 4;

  const bf16* base = qkv + (size_t)b * 1024 * 3072;
  const int qrow0 = qt * 256 + w * 32;

  const float qscale = 0.03125f * 1.44269504f;
  bf16x8 qf[4];
  #pragma unroll
  for (int st = 0; st < 4; st++) {
    const bf16* p = base + (size_t)(qrow0 + l31) * 3072 + h * 64 + st * 16 + hi * 8;
    bf16x8 v = *reinterpret_cast<const bf16x8*>(p);
    #pragma unroll
    for (int e = 0; e < 8; e++) v[e] = (bf16)((float)v[e] * qscale);
    qf[st] = v;
  }

  bf16x8 onesf;
  #pragma unroll
  for (int e = 0; e < 8; e++) onesf[e] = (bf16)1.0f;

  f32x16 acc0 = {}, acc1 = {}, accS = {};

  const int skey  = w * 8 + (l >> 3);
  const int sslot = (l & 7) ^ ((l >> 3) & 7);
  const int vd0   = (tid & 15) * 4;
  const int vk0   = ((tid >> 4) & 15) * 4;
  const int vslot = (tid >> 5) & 7;
  const int vhalf = (tid >> 4) & 1;

  for (int kt = 0; kt < 16; ++kt) {
    __syncthreads();
    gload_lds16(base + (size_t)(kt * 64 + skey) * 3072 + 1024 + h * 64 + sslot * 8,
                (char*)Ks + w * 1024);
    if (tid < 256) {
      bf16x4 vv[4];
      #pragma unroll
      for (int i = 0; i < 4; ++i)
        vv[i] = *reinterpret_cast<const bf16x4*>(
            base + (size_t)(kt * 64 + vk0 + i) * 3072 + 2048 + h * 64 + vd0);
      #pragma unroll
      for (int j = 0; j < 4; ++j) {
        int d = vd0 + j;
        bf16x4 o; o[0] = vv[0][j]; o[1] = vv[1][j]; o[2] = vv[2][j]; o[3] = vv[3][j];
        *reinterpret_cast<bf16x4*>(
            &Vt[d * 64 + ((vslot ^ (d & 7) ^ ((d >> 3) & 7)) * 8 + vhalf * 4)]) = o;
      }
    }
    __syncthreads();

    #pragma unroll
    for (int ktile = 0; ktile < 2; ++ktile) {
      f32x16 s = {};
      const int key = ktile * 32 + l31;
      #pragma unroll
      for (int st = 0; st < 4; ++st) {
        const int slot = (2 * st + hi) ^ (key & 7);
        bf16x8 kf = *reinterpret_cast<const bf16x8*>(&Ks[key * 64 + slot * 8]);
        s = __builtin_amdgcn_mfma_f32_32x32x16_bf16(kf, qf[st], s, 0, 0, 0);
      }
      #pragma unroll
      for (int gq = 0; gq < 4; ++gq) {
        bf16x4 pb;
        #pragma unroll
        for (int j2 = 0; j2 < 4; ++j2) {
          float pv = __builtin_amdgcn_exp2f(s[4 * gq + j2]);
          pb[j2] = (bf16)pv;
        }
        const int chunk = ktile * 4 + gq;
        *reinterpret_cast<bf16x4*>(
            &Pl[w][l31 * 64 + ((chunk ^ (l31 & 7)) * 8 + hi * 4)]) = pb;
      }
    }

    const int d7x0 = (l31 & 7) ^ (l31 >> 3);
    const int d7x1 = d7x0 ^ 4;
    #pragma unroll
    for (int st = 0; st < 4; ++st) {
      const int cs = 2 * st + hi;
      bf16x8 pa  = *reinterpret_cast<const bf16x8*>(
          &Pl[w][l31 * 64 + ((cs ^ (l31 & 7)) * 8)]);
      accS = __builtin_amdgcn_mfma_f32_32x32x16_bf16(pa, onesf, accS, 0, 0, 0);
      bf16x8 vf0 = *reinterpret_cast<const bf16x8*>(
          &Vt[l31 * 64 + ((cs ^ d7x0) * 8)]);
      acc0 = __builtin_amdgcn_mfma_f32_32x32x16_bf16(pa, vf0, acc0, 0, 0, 0);
      bf16x8 vf1 = *reinterpret_cast<const bf16x8*>(
          &Vt[(32 + l31) * 64 + ((cs ^ d7x1) * 8)]);
      acc1 = __builtin_amdgcn_mfma_f32_32x32x16_bf16(pa, vf1, acc1, 0, 0, 0);
    }
  }

  #pragma unroll
  for (int reg = 0; reg < 16; ++reg) {
    int q_r = (reg & 3) + 8 * (reg >> 2) + 4 * hi;
    float rinv = 1.0f / accS[reg];
    size_t rowoff = ((size_t)b * 1024 + qrow0 + q_r) * 1024 + h * 64;
    aout[rowoff + l31]      = (bf16)(acc0[reg] * rinv);
    aout[rowoff + 32 + l31] = (bf16)(acc1[reg] * rinv);
  }
}

// ---------------- launch ----------------

extern "C" void kernel_launch(void* const* d_in, const int* in_sizes, int n_in,
                              void* d_out, int out_size, void* d_ws, size_t ws_size,
                              hipStream_t stream) {
  const float* x     = (const float*)d_in[0];   // [8,1024,1024]
  const float* w_in  = (const float*)d_in[1];   // [1024,3072]
  const float* w_out = (const float*)d_in[2];   // [1024,1024]
  const float* b_out = (const float*)d_in[3];   // [1024]
  float* out = (float*)d_out;                   // [8,1024,1024] fp32

  bf16* xb    = (bf16*)d_ws;                         // 8192*1024
  bf16* wint  = xb    + (size_t)8192 * 1024;         // 3072*1024  (w_in^T)
  bf16* woutt = wint  + (size_t)3072 * 1024;         // 1024*1024  (w_out^T)
  bf16* qkv   = woutt + (size_t)1024 * 1024;         // 8192*3072
  bf16* ao    = qkv   + (size_t)8192 * 3072;         // 8192*1024

  cvt_f32_to_bf16<<<8192, 256, 0, stream>>>(x, xb, 8192 * 1024);
  transpose_cvt<<<dim3(96, 32), dim3(32, 8), 0, stream>>>(w_in,  wint,  1024, 3072);
  transpose_cvt<<<dim3(32, 32), dim3(32, 8), 0, stream>>>(w_out, woutt, 1024, 1024);

  // qkv = x @ w_in   (bf16 out) - 256^2 counted-vmcnt, 384 blocks (32x12)
  gemm256<bf16, false><<<384, 512, 0, stream>>>(xb, wint, nullptr, qkv, 8192, 3072, 1024);

  // fused attention -> ao (bf16, [token][h*64+d]) - 8-wave blocks, 512 total
  attn_fused<<<512, 512, 0, stream>>>(qkv, ao);

  // out = ao @ w_out + b_out   (fp32 out) - 128^2, 512 blocks
  gemm_abt<float, true><<<512, 256, 0, stream>>>(ao, woutt, b_out, out, 8192, 1024, 1024);
}

// Round 14
// 162.305 us; speedup vs baseline: 1.0004x; 1.0004x over previous
//
#include <hip/hip_runtime.h>
#include <stdint.h>
#include <stddef.h>

typedef __bf16 bf16;
typedef __bf16 bf16x4 __attribute__((ext_vector_type(4)));
typedef __bf16 bf16x8 __attribute__((ext_vector_type(8)));
typedef float  f32x4  __attribute__((ext_vector_type(4)));
typedef float  f32x16 __attribute__((ext_vector_type(16)));
typedef float  f32x4v __attribute__((ext_vector_type(4)));

// async global->LDS, 16B per lane, wave-uniform LDS base + lane*16
__device__ __forceinline__ void gload_lds16(const void* g, void* lds) {
  __builtin_amdgcn_global_load_lds(
      (__attribute__((address_space(1))) void*)(uintptr_t)g,
      (__attribute__((address_space(3))) void*)lds,
      16, 0, 0);
}

// ---------------- conversion kernels ----------------

__global__ void cvt_f32_to_bf16(const float* __restrict__ in, bf16* __restrict__ out, int n) {
  int i = (blockIdx.x * blockDim.x + threadIdx.x) * 4;
  if (i >= n) return;
  f32x4v v = *reinterpret_cast<const f32x4v*>(in + i);
  bf16x4 o;
  o[0] = (bf16)v[0]; o[1] = (bf16)v[1]; o[2] = (bf16)v[2]; o[3] = (bf16)v[3];
  *reinterpret_cast<bf16x4*>(out + i) = o;
}

// in [R][C] f32  ->  out [C][R] bf16   (R,C multiples of 32)
__global__ void transpose_cvt(const float* __restrict__ in, bf16* __restrict__ out, int R, int C) {
  __shared__ bf16 tile[32][33];
  int c0 = blockIdx.x * 32, r0 = blockIdx.y * 32;
  int tx = threadIdx.x, ty = threadIdx.y;
  #pragma unroll
  for (int i = ty; i < 32; i += 8)
    tile[i][tx] = (bf16)in[(size_t)(r0 + i) * C + (c0 + tx)];
  __syncthreads();
  #pragma unroll
  for (int i = ty; i < 32; i += 8)
    out[(size_t)(c0 + i) * R + (r0 + tx)] = tile[tx][i];
}

// ---------------- GEMM 128^2 (2-barrier, proven) -- used for GEMM2 ---------

template <typename OT, bool BIAS>
__global__ __launch_bounds__(256) void gemm_abt(
    const bf16* __restrict__ A,   // [M][K]
    const bf16* __restrict__ Bt,  // [N][K]
    const float* __restrict__ bias,
    OT* __restrict__ C, int M, int N, int K)
{
  __shared__ bf16 As[128 * 64];
  __shared__ bf16 Bs[128 * 64];

  const int tid = threadIdx.x;
  const int w = tid >> 6, l = tid & 63;
  const int l15 = l & 15, l4 = l >> 4, l7 = l & 7;
  const int wr = w >> 1, wc = w & 1;

  const int nwgx = N >> 7;
  const int nwg  = (M >> 7) * nwgx;
  const int cpx  = nwg >> 3;
  const int bid  = blockIdx.x;
  const int swz  = (bid & 7) * cpx + (bid >> 3);
  const int m0 = (swz / nwgx) * 128, n0 = (swz % nwgx) * 128;

  f32x4 acc[4][4];
  #pragma unroll
  for (int i = 0; i < 4; i++)
    #pragma unroll
    for (int j = 0; j < 4; j++) acc[i][j] = (f32x4){0.f, 0.f, 0.f, 0.f};

  const int srow  = w * 8 + (l >> 3);
  const int sslot = (l & 7) ^ ((l >> 3) & 7);
  const int KT = K >> 6;

  for (int kt = 0; kt < KT; ++kt) {
    __syncthreads();
    const int kcol = kt * 64 + sslot * 8;
    #pragma unroll
    for (int p = 0; p < 4; ++p) {
      gload_lds16(A  + (size_t)(m0 + p * 32 + srow) * K + kcol,
                  (char*)As + p * 4096 + w * 1024);
      gload_lds16(Bt + (size_t)(n0 + p * 32 + srow) * K + kcol,
                  (char*)Bs + p * 4096 + w * 1024);
    }
    __syncthreads();

    #pragma unroll
    for (int kk = 0; kk < 2; ++kk) {
      const int coff = (kk * 32 + l4 * 8) ^ (l7 << 3);
      bf16x8 af[4], bq[4];
      #pragma unroll
      for (int m = 0; m < 4; ++m) {
        int r = wr * 64 + m * 16 + l15;
        af[m] = *reinterpret_cast<const bf16x8*>(&As[r * 64 + coff]);
      }
      #pragma unroll
      for (int n = 0; n < 4; ++n) {
        int r = wc * 64 + n * 16 + l15;
        bq[n] = *reinterpret_cast<const bf16x8*>(&Bs[r * 64 + coff]);
      }
      #pragma unroll
      for (int m = 0; m < 4; ++m)
        #pragma unroll
        for (int n = 0; n < 4; ++n)
          acc[m][n] = __builtin_amdgcn_mfma_f32_16x16x32_bf16(af[m], bq[n], acc[m][n], 0, 0, 0);
    }
  }

  #pragma unroll
  for (int m = 0; m < 4; ++m) {
    #pragma unroll
    for (int n = 0; n < 4; ++n) {
      int col = n0 + wc * 64 + n * 16 + l15;
      float bv = BIAS ? bias[col] : 0.f;
      #pragma unroll
      for (int j = 0; j < 4; ++j) {
        int row = m0 + wr * 64 + m * 16 + l4 * 4 + j;
        float v = acc[m][n][j] + bv;
        C[(size_t)row * N + col] = (OT)v;
      }
    }
  }
}

// ---------------- GEMM 256^2 counted-vmcnt 4-phase (T2+T3+T4+T5) -----------
// 512 threads = 8 waves (2M x 4N). Phase p=(mh,nh) computes C quadrant
// rows mh*128+wm*64..+63, cols nh*128+wn*32..+31 (16 MFMA) and consumes
// EXACTLY half-tiles A[mh], B[nh]. Staging: one half-tile per phase, one
// K-step ahead, issue order A-lo,B-lo,B-hi,A-hi. Per-wave issue arithmetic
// gives a uniform s_waitcnt vmcnt(6) at phases 0,1,2 (none at 3): each
// phase's needed half-tile is exactly "all but the 6 youngest loads", with
// >=3 phases of landing slack. Never drains to 0 in the main loop (the
// R9 drain-0 mistake = m218's "8-phase-with-drain0 ~ 1-phase").
// Single s_barrier per phase: every LDS region has >=2 barrier crossings
// between last read (drained by that wave's pre-MFMA lgkmcnt) and re-stage.
// asm volatile barriers with "memory" clobber pin the LDS reads after the
// barrier (raw s_barrier builtin carries no fence - rule #18 class).

template <typename OT, bool BIAS>
__global__ __launch_bounds__(512, 1) void gemm256(
    const bf16* __restrict__ A,   // [M][K]
    const bf16* __restrict__ Bt,  // [N][K]
    const float* __restrict__ bias,
    OT* __restrict__ C, int M, int N, int K)
{
  __shared__ bf16 As[2][256 * 64];
  __shared__ bf16 Bs[2][256 * 64];

  const int tid = threadIdx.x;
  const int w = tid >> 6, l = tid & 63;
  const int l15 = l & 15, l4 = l >> 4, l7 = l & 7;
  const int wm = w >> 2, wn = w & 3;

  const int nwgx = N >> 8;
  const int nwg  = (M >> 8) * nwgx;
  const int cpx  = nwg >> 3;
  const int bid  = blockIdx.x;
  const int swz  = (bid & 7) * cpx + (bid >> 3);
  const int m0 = (swz / nwgx) * 256, n0 = (swz % nwgx) * 256;

  f32x4 acc[8][4];   // [mh*4+i][nh*2+n2]
  #pragma unroll
  for (int i = 0; i < 8; i++)
    #pragma unroll
    for (int j = 0; j < 4; j++) acc[i][j] = (f32x4){0.f, 0.f, 0.f, 0.f};

  const int w8l   = w * 8 + (l >> 3);            // row 0..63 within a 64-row block
  const int sslot = (l & 7) ^ ((l >> 3) & 7);
  const int KT = K >> 6;

  // stage half-tile (2 gloads/thread). hoff: 0 = lo(rows/cols 0-127), 128 = hi
  #define STA(t, hoff)                                                          \
    _Pragma("unroll")                                                           \
    for (int q = 0; q < 2; ++q)                                                 \
      gload_lds16(A + (size_t)(m0 + (hoff) + q * 64 + w8l) * K + (t) * 64 + sslot * 8, \
                  (char*)As[(t) & 1] + (hoff) * 128 + q * 8192 + w * 1024);
  #define STB(t, hoff)                                                          \
    _Pragma("unroll")                                                           \
    for (int q = 0; q < 2; ++q)                                                 \
      gload_lds16(Bt + (size_t)(n0 + (hoff) + q * 64 + w8l) * K + (t) * 64 + sslot * 8, \
                  (char*)Bs[(t) & 1] + (hoff) * 128 + q * 8192 + w * 1024);

  // prologue: K-step 0, issue order A-lo, B-lo, B-hi, A-hi
  STA(0, 0); STB(0, 0); STB(0, 128); STA(0, 128);

  bf16x8 afr[4][2], bfr[2][2];

  #define PHASE(buf, mh, nh)                                                     \
    {                                                                            \
      __builtin_amdgcn_s_setprio(1);                                             \
      if ((nh) == 0) {                                                           \
        _Pragma("unroll")                                                        \
        for (int i = 0; i < 4; ++i)                                              \
          _Pragma("unroll")                                                      \
          for (int kk = 0; kk < 2; ++kk) {                                       \
            int r = (mh) * 128 + wm * 64 + i * 16 + l15;                         \
            afr[i][kk] = *reinterpret_cast<const bf16x8*>(                       \
                &As[buf][r * 64 + (((kk * 4 + l4) ^ l7) * 8)]);                  \
          }                                                                      \
      }                                                                          \
      _Pragma("unroll")                                                          \
      for (int n2 = 0; n2 < 2; ++n2)                                             \
        _Pragma("unroll")                                                        \
        for (int kk = 0; kk < 2; ++kk) {                                         \
          int r = (nh) * 128 + wn * 32 + n2 * 16 + l15;                          \
          bfr[n2][kk] = *reinterpret_cast<const bf16x8*>(                        \
              &Bs[buf][r * 64 + (((kk * 4 + l4) ^ l7) * 8)]);                    \
        }                                                                        \
      _Pragma("unroll")                                                          \
      for (int i = 0; i < 4; ++i)                                                \
        _Pragma("unroll")                                                        \
        for (int n2 = 0; n2 < 2; ++n2)                                           \
          _Pragma("unroll")                                                      \
          for (int kk = 0; kk < 2; ++kk)                                         \
            acc[(mh) * 4 + i][(nh) * 2 + n2] =                                   \
                __builtin_amdgcn_mfma_f32_16x16x32_bf16(                         \
                    afr[i][kk], bfr[n2][kk], acc[(mh) * 4 + i][(nh) * 2 + n2],   \
                    0, 0, 0);                                                    \
      __builtin_amdgcn_s_setprio(0);                                             \
    }

  for (int t = 0; t < KT - 1; ++t) {
    const int buf = t & 1;
    // ph0 (0,0): stage A-lo(t+1)
    STA(t + 1, 0);
    asm volatile("s_waitcnt vmcnt(6)" ::: "memory");
    asm volatile("s_barrier" ::: "memory");
    PHASE(buf, 0, 0)
    // ph1 (0,1): stage B-lo(t+1)
    STB(t + 1, 0);
    asm volatile("s_waitcnt vmcnt(6)" ::: "memory");
    asm volatile("s_barrier" ::: "memory");
    PHASE(buf, 0, 1)
    // ph2 (1,0): stage B-hi(t+1)
    STB(t + 1, 128);
    asm volatile("s_waitcnt vmcnt(6)" ::: "memory");
    asm volatile("s_barrier" ::: "memory");
    PHASE(buf, 1, 0)
    // ph3 (1,1): stage A-hi(t+1); no wait needed (A-hi/B-hi already ensured)
    STA(t + 1, 128);
    asm volatile("s_barrier" ::: "memory");
    PHASE(buf, 1, 1)
  }

  // final K-step: everything staged; one drain, then pure compute
  asm volatile("s_waitcnt vmcnt(0)" ::: "memory");
  asm volatile("s_barrier" ::: "memory");
  {
    const int buf = (KT - 1) & 1;
    PHASE(buf, 0, 0)
    PHASE(buf, 0, 1)
    PHASE(buf, 1, 0)
    PHASE(buf, 1, 1)
  }
  #undef PHASE
  #undef STA
  #undef STB

  // epilogue
  #pragma unroll
  for (int mh = 0; mh < 2; ++mh)
    #pragma unroll
    for (int i = 0; i < 4; ++i)
      #pragma unroll
      for (int nh = 0; nh < 2; ++nh)
        #pragma unroll
        for (int n2 = 0; n2 < 2; ++n2) {
          int col = n0 + nh * 128 + wn * 32 + n2 * 16 + l15;
          float bv = BIAS ? bias[col] : 0.f;
          #pragma unroll
          for (int j = 0; j < 4; ++j) {
            int row = m0 + mh * 128 + wm * 64 + i * 16 + l4 * 4 + j;
            C[(size_t)row * N + col] = (OT)(acc[mh * 4 + i][nh * 2 + n2][j] + bv);
          }
        }
}

// ---------------- fused flash attention (32x32x16, 8-wave shared K/V) ------
// unchanged from R12 (best measured)

__global__ __launch_bounds__(512) void attn_fused(
    const bf16* __restrict__ qkv,
    bf16* __restrict__ aout)      // [8192][1024], col = h*64+d
{
  __shared__ bf16 Ks[64 * 64];
  __shared__ bf16 Vt[64 * 64];
  __shared__ bf16 Pl[8][32 * 64];

  const int tid = threadIdx.x;
  const int w = tid >> 6, l = tid & 63;
  const int l31 = l & 31, hi = l >> 5;

  const int bid = blockIdx.x;            // 512 blocks
  const int c  = bid & 7, rr = bid >> 3;
  const int g  = c * 16 + (rr & 15);
  const int qt = rr >> 4;
  const int h  = g & 15;
  const int b  = g >> 4;

  const bf16* base = qkv + (size_t)b * 1024 * 3072;
  const int qrow0 = qt * 256 + w * 32;

  const float qscale = 0.03125f * 1.44269504f;
  bf16x8 qf[4];
  #pragma unroll
  for (int st = 0; st < 4; st++) {
    const bf16* p = base + (size_t)(qrow0 + l31) * 3072 + h * 64 + st * 16 + hi * 8;
    bf16x8 v = *reinterpret_cast<const bf16x8*>(p);
    #pragma unroll
    for (int e = 0; e < 8; e++) v[e] = (bf16)((float)v[e] * qscale);
    qf[st] = v;
  }

  bf16x8 onesf;
  #pragma unroll
  for (int e = 0; e < 8; e++) onesf[e] = (bf16)1.0f;

  f32x16 acc0 = {}, acc1 = {}, accS = {};

  const int skey  = w * 8 + (l >> 3);
  const int sslot = (l & 7) ^ ((l >> 3) & 7);
  const int vd0   = (tid & 15) * 4;
  const int vk0   = ((tid >> 4) & 15) * 4;
  const int vslot = (tid >> 5) & 7;
  const int vhalf = (tid >> 4) & 1;

  for (int kt = 0; kt < 16; ++kt) {
    __syncthreads();
    gload_lds16(base + (size_t)(kt * 64 + skey) * 3072 + 1024 + h * 64 + sslot * 8,
                (char*)Ks + w * 1024);
    if (tid < 256) {
      bf16x4 vv[4];
      #pragma unroll
      for (int i = 0; i < 4; ++i)
        vv[i] = *reinterpret_cast<const bf16x4*>(
            base + (size_t)(kt * 64 + vk0 + i) * 3072 + 2048 + h * 64 + vd0);
      #pragma unroll
      for (int j = 0; j < 4; ++j) {
        int d = vd0 + j;
        bf16x4 o; o[0] = vv[0][j]; o[1] = vv[1][j]; o[2] = vv[2][j]; o[3] = vv[3][j];
        *reinterpret_cast<bf16x4*>(
            &Vt[d * 64 + ((vslot ^ (d & 7) ^ ((d >> 3) & 7)) * 8 + vhalf * 4)]) = o;
      }
    }
    __syncthreads();

    #pragma unroll
    for (int ktile = 0; ktile < 2; ++ktile) {
      f32x16 s = {};
      const int key = ktile * 32 + l31;
      #pragma unroll
      for (int st = 0; st < 4; ++st) {
        const int slot = (2 * st + hi) ^ (key & 7);
        bf16x8 kf = *reinterpret_cast<const bf16x8*>(&Ks[key * 64 + slot * 8]);
        s = __builtin_amdgcn_mfma_f32_32x32x16_bf16(kf, qf[st], s, 0, 0, 0);
      }
      #pragma unroll
      for (int gq = 0; gq < 4; ++gq) {
        bf16x4 pb;
        #pragma unroll
        for (int j2 = 0; j2 < 4; ++j2) {
          float pv = __builtin_amdgcn_exp2f(s[4 * gq + j2]);
          pb[j2] = (bf16)pv;
        }
        const int chunk = ktile * 4 + gq;
        *reinterpret_cast<bf16x4*>(
            &Pl[w][l31 * 64 + ((chunk ^ (l31 & 7)) * 8 + hi * 4)]) = pb;
      }
    }

    const int d7x0 = (l31 & 7) ^ (l31 >> 3);
    const int d7x1 = d7x0 ^ 4;
    #pragma unroll
    for (int st = 0; st < 4; ++st) {
      const int cs = 2 * st + hi;
      bf16x8 pa  = *reinterpret_cast<const bf16x8*>(
          &Pl[w][l31 * 64 + ((cs ^ (l31 & 7)) * 8)]);
      accS = __builtin_amdgcn_mfma_f32_32x32x16_bf16(pa, onesf, accS, 0, 0, 0);
      bf16x8 vf0 = *reinterpret_cast<const bf16x8*>(
          &Vt[l31 * 64 + ((cs ^ d7x0) * 8)]);
      acc0 = __builtin_amdgcn_mfma_f32_32x32x16_bf16(pa, vf0, acc0, 0, 0, 0);
      bf16x8 vf1 = *reinterpret_cast<const bf16x8*>(
          &Vt[(32 + l31) * 64 + ((cs ^ d7x1) * 8)]);
      acc1 = __builtin_amdgcn_mfma_f32_32x32x16_bf16(pa, vf1, acc1, 0, 0, 0);
    }
  }

  #pragma unroll
  for (int reg = 0; reg < 16; ++reg) {
    int q_r = (reg & 3) + 8 * (reg >> 2) + 4 * hi;
    float rinv = 1.0f / accS[reg];
    size_t rowoff = ((size_t)b * 1024 + qrow0 + q_r) * 1024 + h * 64;
    aout[rowoff + l31]      = (bf16)(acc0[reg] * rinv);
    aout[rowoff + 32 + l31] = (bf16)(acc1[reg] * rinv);
  }
}

// ---------------- launch ----------------

extern "C" void kernel_launch(void* const* d_in, const int* in_sizes, int n_in,
                              void* d_out, int out_size, void* d_ws, size_t ws_size,
                              hipStream_t stream) {
  const float* x     = (const float*)d_in[0];   // [8,1024,1024]
  const float* w_in  = (const float*)d_in[1];   // [1024,3072]
  const float* w_out = (const float*)d_in[2];   // [1024,1024]
  const float* b_out = (const float*)d_in[3];   // [1024]
  float* out = (float*)d_out;                   // [8,1024,1024] fp32

  bf16* xb    = (bf16*)d_ws;                         // 8192*1024
  bf16* wint  = xb    + (size_t)8192 * 1024;         // 3072*1024  (w_in^T)
  bf16* woutt = wint  + (size_t)3072 * 1024;         // 1024*1024  (w_out^T)
  bf16* qkv   = woutt + (size_t)1024 * 1024;         // 8192*3072
  bf16* ao    = qkv   + (size_t)8192 * 3072;         // 8192*1024

  cvt_f32_to_bf16<<<8192, 256, 0, stream>>>(x, xb, 8192 * 1024);
  transpose_cvt<<<dim3(96, 32), dim3(32, 8), 0, stream>>>(w_in,  wint,  1024, 3072);
  transpose_cvt<<<dim3(32, 32), dim3(32, 8), 0, stream>>>(w_out, woutt, 1024, 1024);

  // qkv = x @ w_in   (bf16 out) - 256^2 counted-vmcnt, 384 blocks (32x12)
  gemm256<bf16, false><<<384, 512, 0, stream>>>(xb, wint, nullptr, qkv, 8192, 3072, 1024);

  // fused attention -> ao (bf16, [token][h*64+d]) - 8-wave blocks, 512 total
  attn_fused<<<512, 512, 0, stream>>>(qkv, ao);

  // out = ao @ w_out + b_out   (fp32 out) - 128^2, 512 blocks
  gemm_abt<float, true><<<512, 256, 0, stream>>>(ao, woutt, b_out, out, 8192, 1024, 1024);
}